// Round 4
// baseline (129.235 us; speedup 1.0000x reference)
//
#include <hip/hip_runtime.h>

#define IN_DIM 8192
#define OUT_DIM 8192
#define BATCH 2048

#define TPB 512                      // 8 waves/block
#define JT 2                         // j-tiles per row (each block covers OUT_DIM/JT outputs)
#define JTILE (OUT_DIM / JT)         // 4096 outputs per block
#define OPT (JTILE / TPB / 4)        // 2 float4-outputs per thread (register-cached coeffs)
#define RROWS 8                      // rows per block -> grid = JT * BATCH/RROWS = 512 blocks
#define SVEC (IN_DIM / 4 / TPB)      // 4 staging float4 per thread per row

typedef float fvec4 __attribute__((ext_vector_type(4)));

// Barrier WITHOUT the vmcnt(0) drain __syncthreads() would emit:
// waits only for our LDS ops, leaves global prefetch loads in flight.
#define BAR() __asm__ __volatile__("s_waitcnt lgkmcnt(0)\n\ts_barrier" ::: "memory")

// ---------------------------------------------------------------------------
// Kernel 1: softmax(16) per output unit -> 4 affine coefficients {1,a,b,ab}.
// ---------------------------------------------------------------------------
__global__ __launch_bounds__(256) void coeff_kernel(
    const float* __restrict__ w,
    float* __restrict__ c0, float* __restrict__ ca,
    float* __restrict__ cb, float* __restrict__ cab)
{
    int j = blockIdx.x * blockDim.x + threadIdx.x;
    if (j >= OUT_DIM) return;

    const float* wj = w + (size_t)j * 16;
    float wv[16];
    float m = -1e30f;
#pragma unroll
    for (int k = 0; k < 16; ++k) { wv[k] = wj[k]; m = fmaxf(m, wv[k]); }
    float s = 0.f;
#pragma unroll
    for (int k = 0; k < 16; ++k) { wv[k] = __expf(wv[k] - m); s += wv[k]; }
    float inv = 1.0f / s;
#pragma unroll
    for (int k = 0; k < 16; ++k) wv[k] *= inv;

    c0[j]  = wv[8] + wv[9] + wv[10] + wv[11] + wv[12] + wv[13] + wv[14] + wv[15];
    ca[j]  = wv[2] + wv[3] + wv[6] + wv[7] - wv[8] - wv[9] - wv[12] - wv[13];
    cb[j]  = wv[4] + wv[5] + wv[6] + wv[7] - wv[8] - wv[9] - wv[10] - wv[11];
    cab[j] = wv[1] - wv[2] - wv[4] - 2.f * wv[6] - wv[7]
           + wv[8] + 2.f * wv[9] + wv[11] + wv[13] - wv[14];
}

// ---------------------------------------------------------------------------
// Kernel 2: block = (j-half-tile, 8 rows). idx+coeffs cached in registers
// once; rows pipelined through double-buffered LDS with prefetch-in-registers
// issued during the previous row's compute. One no-vmcnt barrier per row.
// ---------------------------------------------------------------------------
__global__ __launch_bounds__(TPB, 4) void logic_kernel(
    const float* __restrict__ x,
    const int* __restrict__ idx_a,
    const int* __restrict__ idx_b,
    const float* __restrict__ c0, const float* __restrict__ ca,
    const float* __restrict__ cb, const float* __restrict__ cab,
    float* __restrict__ out)
{
    __shared__ float xrow[2][IN_DIM];        // 64 KB -> 2 blocks/CU

    const int jt    = blockIdx.x & (JT - 1);
    const int rg    = blockIdx.x / JT;
    const int row0  = rg * RROWS;
    const int jb4   = jt * (JTILE / 4);      // float4-index base of our j-tile
    const int tid   = threadIdx.x;

    // ---- prologue: cache this j-tile's idx + coefficients in registers ----
    const int4*   ia4  = (const int4*)idx_a;
    const int4*   ib4  = (const int4*)idx_b;
    const float4* c04  = (const float4*)c0;
    const float4* ca4  = (const float4*)ca;
    const float4* cb4  = (const float4*)cb;
    const float4* cab4 = (const float4*)cab;

    int4   ia[OPT], ib[OPT];
    float4 v0[OPT], va[OPT], vb[OPT], vab[OPT];
#pragma unroll
    for (int it = 0; it < OPT; ++it) {
        int j4  = jb4 + it * TPB + tid;
        ia[it]  = ia4[j4];
        ib[it]  = ib4[j4];
        v0[it]  = c04[j4];
        va[it]  = ca4[j4];
        vb[it]  = cb4[j4];
        vab[it] = cab4[j4];
    }

    // ---- prefetch row 0 into registers ----
    float4 pf[SVEC];
    {
        const float4* xr4 = (const float4*)(x + (size_t)row0 * IN_DIM);
#pragma unroll
        for (int k = 0; k < SVEC; ++k) pf[k] = xr4[k * TPB + tid];
    }

    for (int r = 0; r < RROWS; ++r) {
        // write the prefetched row into this parity's LDS buffer
        float4* buf4 = (float4*)xrow[r & 1];
#pragma unroll
        for (int k = 0; k < SVEC; ++k) buf4[k * TPB + tid] = pf[k];

        // issue next row's global loads NOW — they stay in flight across the
        // barrier (no vmcnt drain) and the whole compute phase below.
        if (r + 1 < RROWS) {
            const float4* xr4 = (const float4*)(x + (size_t)(row0 + r + 1) * IN_DIM);
#pragma unroll
            for (int k = 0; k < SVEC; ++k) pf[k] = xr4[k * TPB + tid];
        }

        BAR();   // lgkmcnt(0)+s_barrier: LDS row visible; prefetch NOT drained

        const float* xr = xrow[r & 1];
        fvec4* out4 = (fvec4*)(out + (size_t)(row0 + r) * OUT_DIM);
#pragma unroll
        for (int it = 0; it < OPT; ++it) {
            int j4 = jb4 + it * TPB + tid;

            float a0 = xr[ia[it].x], b0 = xr[ib[it].x];
            float a1 = xr[ia[it].y], b1 = xr[ib[it].y];
            float a2 = xr[ia[it].z], b2 = xr[ib[it].z];
            float a3 = xr[ia[it].w], b3 = xr[ib[it].w];

            fvec4 o;
            o.x = v0[it].x + va[it].x * a0 + vb[it].x * b0 + vab[it].x * (a0 * b0);
            o.y = v0[it].y + va[it].y * a1 + vb[it].y * b1 + vab[it].y * (a1 * b1);
            o.z = v0[it].z + va[it].z * a2 + vb[it].z * b2 + vab[it].z * (a2 * b2);
            o.w = v0[it].w + va[it].w * a3 + vb[it].w * b3 + vab[it].w * (a3 * b3);
            __builtin_nontemporal_store(o, &out4[j4]);
        }
        // No second barrier: the next iteration's ds_writes hit the OTHER
        // parity buffer, and the single barrier keeps waves within one
        // segment, so write-after-read across parities cannot occur.
    }
}

extern "C" void kernel_launch(void* const* d_in, const int* in_sizes, int n_in,
                              void* d_out, int out_size, void* d_ws, size_t ws_size,
                              hipStream_t stream)
{
    const float* x       = (const float*)d_in[0];  // (2048, 8192) fp32
    const float* weights = (const float*)d_in[1];  // (8192, 16)   fp32
    const int*   idx_a   = (const int*)d_in[2];    // (8192,) int32
    const int*   idx_b   = (const int*)d_in[3];    // (8192,) int32
    float* out = (float*)d_out;                    // (2048, 8192) fp32

    float* wsF = (float*)d_ws;
    float* c0  = wsF;
    float* ca  = wsF + OUT_DIM;
    float* cb  = wsF + 2 * OUT_DIM;
    float* cab = wsF + 3 * OUT_DIM;

    coeff_kernel<<<OUT_DIM / 256, 256, 0, stream>>>(weights, c0, ca, cb, cab);
    logic_kernel<<<JT * (BATCH / RROWS), TPB, 0, stream>>>(
        x, idx_a, idx_b, c0, ca, cb, cab, out);
}

// Round 5
// 126.242 us; speedup vs baseline: 1.0237x; 1.0237x over previous
//
#include <hip/hip_runtime.h>

#define IN_DIM 8192
#define OUT_DIM 8192
#define BATCH 2048

#define TPB 512                      // 8 waves/block
#define JT 2                         // j-tiles per row
#define JTILE (OUT_DIM / JT)         // 4096 outputs per block
#define OPT (JTILE / TPB / 4)        // 2 float4-outputs per thread
#define RROWS 4                      // rows per block -> grid = JT * BATCH/RROWS = 1024
#define SVEC (IN_DIM / 4 / TPB)      // 4 staging float4 per thread per row

typedef float fvec4 __attribute__((ext_vector_type(4)));

// Barrier WITHOUT the vmcnt(0) drain __syncthreads() would emit:
// waits only for our LDS ops, leaves global prefetch loads in flight.
#define BAR() __asm__ __volatile__("s_waitcnt lgkmcnt(0)\n\ts_barrier" ::: "memory")

// ---------------------------------------------------------------------------
// Kernel 1: softmax(16) per output unit -> 4 affine coefficients {1,a,b,ab}.
// ---------------------------------------------------------------------------
__global__ __launch_bounds__(256) void coeff_kernel(
    const float* __restrict__ w,
    float* __restrict__ c0, float* __restrict__ ca,
    float* __restrict__ cb, float* __restrict__ cab)
{
    int j = blockIdx.x * blockDim.x + threadIdx.x;
    if (j >= OUT_DIM) return;

    const float* wj = w + (size_t)j * 16;
    float wv[16];
    float m = -1e30f;
#pragma unroll
    for (int k = 0; k < 16; ++k) { wv[k] = wj[k]; m = fmaxf(m, wv[k]); }
    float s = 0.f;
#pragma unroll
    for (int k = 0; k < 16; ++k) { wv[k] = __expf(wv[k] - m); s += wv[k]; }
    float inv = 1.0f / s;
#pragma unroll
    for (int k = 0; k < 16; ++k) wv[k] *= inv;

    c0[j]  = wv[8] + wv[9] + wv[10] + wv[11] + wv[12] + wv[13] + wv[14] + wv[15];
    ca[j]  = wv[2] + wv[3] + wv[6] + wv[7] - wv[8] - wv[9] - wv[12] - wv[13];
    cb[j]  = wv[4] + wv[5] + wv[6] + wv[7] - wv[8] - wv[9] - wv[10] - wv[11];
    cab[j] = wv[1] - wv[2] - wv[4] - 2.f * wv[6] - wv[7]
           + wv[8] + 2.f * wv[9] + wv[11] + wv[13] - wv[14];
}

// ---------------------------------------------------------------------------
// Kernel 2: block = (j-half-tile, 4 rows). idx+coeffs cached in registers
// once; rows pipelined through double-buffered LDS with DEPTH-2 register
// prefetch: the load for row r+2 is issued two barrier segments before its
// vmcnt wait (~2x HBM latency of slack). One lgkm-only barrier per row.
// ---------------------------------------------------------------------------
__global__ __launch_bounds__(TPB, 4) void logic_kernel(
    const float* __restrict__ x,
    const int* __restrict__ idx_a,
    const int* __restrict__ idx_b,
    const float* __restrict__ c0, const float* __restrict__ ca,
    const float* __restrict__ cb, const float* __restrict__ cab,
    float* __restrict__ out)
{
    __shared__ float xrow[2][IN_DIM];        // 64 KB -> 2 blocks/CU

    const int jt    = blockIdx.x & (JT - 1);
    const int rg    = blockIdx.x / JT;
    const int row0  = rg * RROWS;
    const int jb4   = jt * (JTILE / 4);      // float4-index base of our j-tile
    const int tid   = threadIdx.x;

    // ---- prologue: cache this j-tile's idx + coefficients in registers ----
    const int4*   ia4  = (const int4*)idx_a;
    const int4*   ib4  = (const int4*)idx_b;
    const float4* c04  = (const float4*)c0;
    const float4* ca4  = (const float4*)ca;
    const float4* cb4  = (const float4*)cb;
    const float4* cab4 = (const float4*)cab;

    int4   ia[OPT], ib[OPT];
    float4 v0[OPT], va[OPT], vb[OPT], vab[OPT];
#pragma unroll
    for (int it = 0; it < OPT; ++it) {
        int j4  = jb4 + it * TPB + tid;
        ia[it]  = ia4[j4];
        ib[it]  = ib4[j4];
        v0[it]  = c04[j4];
        va[it]  = ca4[j4];
        vb[it]  = cb4[j4];
        vab[it] = cab4[j4];
    }

    // ---- depth-2 prefetch: rows 0 and 1 in flight before the loop ----
    float4 pf[2][SVEC];
#pragma unroll
    for (int p = 0; p < 2; ++p) {
        const float4* xr4 = (const float4*)(x + (size_t)(row0 + p) * IN_DIM);
#pragma unroll
        for (int k = 0; k < SVEC; ++k) pf[p][k] = xr4[k * TPB + tid];
    }

#pragma unroll
    for (int r = 0; r < RROWS; ++r) {
        const int p = r & 1;

        // write the prefetched row into this parity's LDS buffer
        // (vmcnt wait here is for loads issued TWO segments ago)
        float4* buf4 = (float4*)xrow[p];
#pragma unroll
        for (int k = 0; k < SVEC; ++k) buf4[k * TPB + tid] = pf[p][k];

        // refill this parity's prefetch regs with row r+2 — stays in flight
        // across the (no-vmcnt) barrier and the next two phases.
        if (r + 2 < RROWS) {
            const float4* xr4 = (const float4*)(x + (size_t)(row0 + r + 2) * IN_DIM);
#pragma unroll
            for (int k = 0; k < SVEC; ++k) pf[p][k] = xr4[k * TPB + tid];
        }

        BAR();   // lgkmcnt(0)+s_barrier: LDS row visible; prefetch NOT drained

        const float* xr = xrow[p];
        fvec4* out4 = (fvec4*)(out + (size_t)(row0 + r) * OUT_DIM);
#pragma unroll
        for (int it = 0; it < OPT; ++it) {
            int j4 = jb4 + it * TPB + tid;

            float a0 = xr[ia[it].x], b0 = xr[ib[it].x];
            float a1 = xr[ia[it].y], b1 = xr[ib[it].y];
            float a2 = xr[ia[it].z], b2 = xr[ib[it].z];
            float a3 = xr[ia[it].w], b3 = xr[ib[it].w];

            fvec4 o;
            o.x = v0[it].x + va[it].x * a0 + vb[it].x * b0 + vab[it].x * (a0 * b0);
            o.y = v0[it].y + va[it].y * a1 + vb[it].y * b1 + vab[it].y * (a1 * b1);
            o.z = v0[it].z + va[it].z * a2 + vb[it].z * b2 + vab[it].z * (a2 * b2);
            o.w = v0[it].w + va[it].w * a3 + vb[it].w * b3 + vab[it].w * (a3 * b3);
            __builtin_nontemporal_store(o, &out4[j4]);
        }
        // Single barrier per row is safe: the next iteration's ds_writes hit
        // the OTHER parity buffer, and the barrier bounds wave skew to one
        // segment, so write-after-read across parities cannot occur.
    }
}

extern "C" void kernel_launch(void* const* d_in, const int* in_sizes, int n_in,
                              void* d_out, int out_size, void* d_ws, size_t ws_size,
                              hipStream_t stream)
{
    const float* x       = (const float*)d_in[0];  // (2048, 8192) fp32
    const float* weights = (const float*)d_in[1];  // (8192, 16)   fp32
    const int*   idx_a   = (const int*)d_in[2];    // (8192,) int32
    const int*   idx_b   = (const int*)d_in[3];    // (8192,) int32
    float* out = (float*)d_out;                    // (2048, 8192) fp32

    float* wsF = (float*)d_ws;
    float* c0  = wsF;
    float* ca  = wsF + OUT_DIM;
    float* cb  = wsF + 2 * OUT_DIM;
    float* cab = wsF + 3 * OUT_DIM;

    coeff_kernel<<<OUT_DIM / 256, 256, 0, stream>>>(weights, c0, ca, cb, cab);
    logic_kernel<<<JT * (BATCH / RROWS), TPB, 0, stream>>>(
        x, idx_a, idx_b, c0, ca, cb, cab, out);
}